// Round 3
// baseline (73.187 us; speedup 1.0000x reference)
//
#include <hip/hip_runtime.h>
#include <math.h>

#define TPB 256

// Stable-descending comparator: higher value wins; equal values -> smaller
// original index wins (matches jnp.argsort(-scores) stability).
__device__ __forceinline__ bool better(float v1, int i1, float v2, int i2) {
    return (v1 > v2) || (v1 == v2 && i1 < i2);
}

// Fully-unrolled top-5 insert on named scalars (descending t0>=..>=t4).
// STATIC indices only — no private arrays (they'd go to scratch, rule #20).
// Strict > keeps stability when elements are processed in ascending index order.
#define INSERT(v, idx)                                                      \
    if ((v) > t4) {                                                         \
        if ((v) > t2) {                                                     \
            t4 = t3; i4 = i3; t3 = t2; i3 = i2;                             \
            if ((v) > t1) {                                                 \
                t2 = t1; i2 = i1;                                           \
                if ((v) > t0) { t1 = t0; i1 = i0; t0 = (v); i0 = (idx); }   \
                else          { t1 = (v); i1 = (idx); }                     \
            } else { t2 = (v); i2 = (idx); }                                \
        } else {                                                            \
            if ((v) > t3) { t4 = t3; i4 = i3; t3 = (v); i3 = (idx); }       \
            else          { t4 = (v); i4 = (idx); }                         \
        }                                                                   \
    }

// Comparator-based insert for pass 2 (candidates arrive in arbitrary order).
#define INSERT2(v, idx)                                                          \
    if (better((v), (idx), t4, i4)) {                                            \
        if (better((v), (idx), t2, i2)) {                                        \
            t4 = t3; i4 = i3; t3 = t2; i3 = i2;                                  \
            if (better((v), (idx), t1, i1)) {                                    \
                t2 = t1; i2 = i1;                                                \
                if (better((v), (idx), t0, i0)) {                                \
                    t1 = t0; i1 = i0; t0 = (v); i0 = (idx);                      \
                } else { t1 = (v); i1 = (idx); }                                 \
            } else { t2 = (v); i2 = (idx); }                                     \
        } else {                                                                 \
            if (better((v), (idx), t3, i3)) { t4 = t3; i4 = i3; t3 = (v); i3 = (idx); } \
            else                            { t4 = (v); i4 = (idx); }            \
        }                                                                        \
    }

// Process one loaded quad (values already in registers).
#define PROC(p, t, r, ii)                                                   \
    {                                                                       \
        float d;                                                            \
        d = p.x - t.x; accb = fmaf(d, d, accb);                             \
        d = p.y - t.y; accb = fmaf(d, d, accb);                             \
        d = p.z - t.z; accb = fmaf(d, d, accb);                             \
        d = p.w - t.w; accb = fmaf(d, d, accb);                             \
        accr += (r.x >= 2.0f ? r.x : 0.0f) + (r.y >= 2.0f ? r.y : 0.0f)     \
              + (r.z >= 2.0f ? r.z : 0.0f) + (r.w >= 2.0f ? r.w : 0.0f);    \
        float m = fmaxf(fmaxf(p.x, p.y), fmaxf(p.z, p.w));                  \
        if (m > t4) {                                                       \
            const int b = (ii) * 4;                                         \
            INSERT(p.x, b);                                                 \
            INSERT(p.y, b + 1);                                             \
            INSERT(p.z, b + 2);                                             \
            INSERT(p.w, b + 3);                                             \
        }                                                                   \
    }

__global__ __launch_bounds__(TPB) void reward_pass1(
        const float* __restrict__ pred,
        const float* __restrict__ tru,
        const float* __restrict__ ret,
        double* __restrict__ blk_sum,
        float* __restrict__ cand_v,
        int* __restrict__ cand_i,
        int n) {
    const int tid = blockIdx.x * blockDim.x + threadIdx.x;
    const int nthreads = gridDim.x * blockDim.x;
    const int n4 = n >> 2;

    const float4* __restrict__ pred4 = (const float4*)pred;
    const float4* __restrict__ tru4  = (const float4*)tru;
    const float4* __restrict__ ret4  = (const float4*)ret;

    float accb = 0.0f;   // sum of (pred-true)^2
    float accr = 0.0f;   // sum of ret where ret >= 2 (rest_adj = 0.0015 * that)
    float t0 = -INFINITY, t1 = -INFINITY, t2 = -INFINITY, t3 = -INFINITY, t4 = -INFINITY;
    int   i0 = 0x7fffffff, i1 = 0x7fffffff, i2 = 0x7fffffff, i3 = 0x7fffffff, i4 = 0x7fffffff;

    // Depth-4 batch: issue 12 x 16B loads into named registers (12 KB/wave in
    // flight) BEFORE any processing. This is the MLP the R2 kernel lacked
    // (VGPR_Count=24 => ~2 loads in flight => latency-bound at 44% of BW).
    int i = tid;
    for (; i + 3 * nthreads < n4; i += 4 * nthreads) {
        const int ia = i;
        const int ib = i + nthreads;
        const int ic = i + 2 * nthreads;
        const int id = i + 3 * nthreads;
        float4 pa = pred4[ia], pb = pred4[ib], pc = pred4[ic], pd = pred4[id];
        float4 ta = tru4[ia],  tb = tru4[ib],  tc = tru4[ic],  td = tru4[id];
        float4 ra = ret4[ia],  rb = ret4[ib],  rc = ret4[ic],  rd = ret4[id];
        PROC(pa, ta, ra, ia);
        PROC(pb, tb, rb, ib);
        PROC(pc, tc, rc, ic);
        PROC(pd, td, rd, id);
    }
    for (; i < n4; i += nthreads) {
        float4 p = pred4[i];
        float4 t = tru4[i];
        float4 r = ret4[i];
        PROC(p, t, r, i);
    }

    // Scalar tail (n not multiple of 4), handled by global thread 0.
    if (tid == 0) {
        for (int k = n4 * 4; k < n; ++k) {
            float d = pred[k] - tru[k];
            accb = fmaf(d, d, accb);
            float rr = ret[k];
            accr += (rr >= 2.0f ? rr : 0.0f);
            float v = pred[k];
            INSERT(v, k);
        }
    }

    const int lane = threadIdx.x & 63;
    const int wid  = threadIdx.x >> 6;

    // Block sum: wave shuffle reduce (double), then 4 wave partials via LDS.
    double acc = (double)accb + 0.0015 * (double)accr;
    for (int off = 32; off > 0; off >>= 1) acc += __shfl_down(acc, off);
    __shared__ double wsum[4];
    if (lane == 0) wsum[wid] = acc;
    __syncthreads();
    if (threadIdx.x == 0)
        blk_sum[blockIdx.x] = wsum[0] + wsum[1] + wsum[2] + wsum[3];

    // Block top-5: 5 rounds of (wave shfl argmax -> cross-wave via LDS -> pop head).
    __shared__ float bsv[4];
    __shared__ int   bsi[4];
    for (int r = 0; r < 5; ++r) {
        const float cv = t0;
        const int   ci = i0;
        float wv = cv;
        int   wi = ci;
        for (int off = 1; off < 64; off <<= 1) {
            float ov = __shfl_xor(wv, off);
            int   oi = __shfl_xor(wi, off);
            if (better(ov, oi, wv, wi)) { wv = ov; wi = oi; }
        }
        if (lane == 0) { bsv[wid] = wv; bsi[wid] = wi; }
        __syncthreads();
        float gv = bsv[0]; int gi = bsi[0];
        if (better(bsv[1], bsi[1], gv, gi)) { gv = bsv[1]; gi = bsi[1]; }
        if (better(bsv[2], bsi[2], gv, gi)) { gv = bsv[2]; gi = bsi[2]; }
        if (better(bsv[3], bsi[3], gv, gi)) { gv = bsv[3]; gi = bsi[3]; }
        if (threadIdx.x == 0) {
            cand_v[blockIdx.x * 5 + r] = gv;
            cand_i[blockIdx.x * 5 + r] = gi;
        }
        if (gi == ci) {  // indices unique -> only the owning thread pops
            t0 = t1; i0 = i1; t1 = t2; i1 = i2; t2 = t3; i2 = i3;
            t3 = t4; i3 = i4; t4 = -INFINITY; i4 = 0x7fffffff;
        }
        __syncthreads();  // WAR: bsv/bsi reused next round
    }
}

__global__ __launch_bounds__(TPB) void reward_pass2(
        const double* __restrict__ blk_sum,
        const float* __restrict__ cand_v,
        const int* __restrict__ cand_i,
        const float* __restrict__ ret,
        float* __restrict__ out,
        int nb, int n) {
    const int lane = threadIdx.x & 63;
    const int wid  = threadIdx.x >> 6;

    // Sum of partials.
    double acc = 0.0;
    for (int i = threadIdx.x; i < nb; i += TPB) acc += blk_sum[i];
    for (int off = 32; off > 0; off >>= 1) acc += __shfl_down(acc, off);
    __shared__ double wsum[4];
    if (lane == 0) wsum[wid] = acc;
    __syncthreads();

    // Per-thread top-5 over candidates (arbitrary order -> comparator insert).
    float t0 = -INFINITY, t1 = -INFINITY, t2 = -INFINITY, t3 = -INFINITY, t4 = -INFINITY;
    int   i0 = 0x7fffffff, i1 = 0x7fffffff, i2 = 0x7fffffff, i3 = 0x7fffffff, i4 = 0x7fffffff;
    const int nc = nb * 5;
    for (int i = threadIdx.x; i < nc; i += TPB) {
        float v = cand_v[i];
        int idx = cand_i[i];
        INSERT2(v, idx);
    }

    // 5 rounds block argmax + pop -> global top-5.
    __shared__ float bsv[4];
    __shared__ int   bsi[4];
    __shared__ int   winner[5];
    for (int r = 0; r < 5; ++r) {
        const float cv = t0;
        const int   ci = i0;
        float wv = cv;
        int   wi = ci;
        for (int off = 1; off < 64; off <<= 1) {
            float ov = __shfl_xor(wv, off);
            int   oi = __shfl_xor(wi, off);
            if (better(ov, oi, wv, wi)) { wv = ov; wi = oi; }
        }
        if (lane == 0) { bsv[wid] = wv; bsi[wid] = wi; }
        __syncthreads();
        float gv = bsv[0]; int gi = bsi[0];
        if (better(bsv[1], bsi[1], gv, gi)) { gv = bsv[1]; gi = bsi[1]; }
        if (better(bsv[2], bsi[2], gv, gi)) { gv = bsv[2]; gi = bsi[2]; }
        if (better(bsv[3], bsi[3], gv, gi)) { gv = bsv[3]; gi = bsi[3]; }
        if (threadIdx.x == 0) winner[r] = gi;
        if (gi == ci) {
            t0 = t1; i0 = i1; t1 = t2; i1 = i2; t2 = t3; i2 = i3;
            t3 = t4; i3 = i4; t4 = -INFINITY; i4 = 0x7fffffff;
        }
        __syncthreads();
    }

    if (threadIdx.x == 0) {
        double corr = 0.0;
        for (int r = 0; r < 5; ++r) {
            int idx = winner[r];
            float rr = ret[idx];
            float a = fabsf(rr);
            float strict, mid;
            if (rr < 0.0f)       { strict = 0.005f * a;  mid = 0.0025f * a; }
            else if (rr >= 2.0f) { strict = -0.02f * rr; mid = -0.01f * rr; }
            else if (rr > 0.0f)  { strict = -0.01f * rr; mid = -0.005f * rr; }
            else                 { strict = 0.0f;        mid = 0.0f; }
            float rest = (rr >= 2.0f) ? 0.0015f * rr : 0.0f;
            float bucket = (r < 3) ? strict : mid;  // ranks 1..3 strict, 4..5 mid
            corr += (double)(bucket - rest);
        }
        out[0] = (float)((wsum[0] + wsum[1] + wsum[2] + wsum[3] + corr) / (double)n);
    }
}

extern "C" void kernel_launch(void* const* d_in, const int* in_sizes, int n_in,
                              void* d_out, int out_size, void* d_ws, size_t ws_size,
                              hipStream_t stream) {
    const float* pred = (const float*)d_in[0];
    const float* tru  = (const float*)d_in[1];
    const float* ret  = (const float*)d_in[2];
    float* out = (float*)d_out;
    const int n = in_sizes[0];

    int nb = 2048;
    // Per-block scratch: 8B sum + 5*(4+4)B candidates = 48B. Fit within ws_size.
    while (nb > 64 && (size_t)nb * 48 > ws_size) nb >>= 1;

    double* blk_sum = (double*)d_ws;
    float*  cand_v  = (float*)(blk_sum + nb);
    int*    cand_i  = (int*)(cand_v + (size_t)nb * 5);

    reward_pass1<<<nb, TPB, 0, stream>>>(pred, tru, ret, blk_sum, cand_v, cand_i, n);
    reward_pass2<<<1, TPB, 0, stream>>>(blk_sum, cand_v, cand_i, ret, out, nb, n);
}

// Round 4
// 62.840 us; speedup vs baseline: 1.1647x; 1.1647x over previous
//
#include <hip/hip_runtime.h>
#include <math.h>

#define TPB 256

typedef unsigned long long u64;
typedef unsigned int u32;

// Packed sort key: strictly increasing in value; ties -> smaller index wins.
// u64 compare (>) == better(v1,i1,v2,i2) from jnp.argsort(-scores) stability.
__device__ __forceinline__ u64 mkkey(float v, int idx) {
    u32 u = __float_as_uint(v);
    u ^= (u32)(((int)u) >> 31) | 0x80000000u;   // monotone float->uint map
    return ((u64)u << 32) | (u32)(~idx);
}

// Branchless top-5 update on named u64 scalars (k0 >= k1 >= ... >= k4).
// Select ladder, no CFG, no private arrays (rule #20 / CFG-kills-MLP lesson).
#define UPD(v, idx)                                             \
    {                                                           \
        const u64 _key = mkkey((v), (idx));                     \
        const bool c0 = _key > k0;                              \
        const bool c1 = _key > k1;                              \
        const bool c2 = _key > k2;                              \
        const bool c3 = _key > k3;                              \
        const bool c4 = _key > k4;                              \
        k4 = c3 ? k3 : (c4 ? _key : k4);                        \
        k3 = c2 ? k2 : (c3 ? _key : k3);                        \
        k2 = c1 ? k1 : (c2 ? _key : k2);                        \
        k1 = c0 ? k0 : (c1 ? _key : k1);                        \
        k0 = c0 ? _key : k0;                                    \
    }

// Process one loaded quad (values already in registers). Fully branchless.
#define PROC(p, t, r, ii)                                                   \
    {                                                                       \
        float d;                                                            \
        d = p.x - t.x; accb = fmaf(d, d, accb);                             \
        d = p.y - t.y; accb = fmaf(d, d, accb);                             \
        d = p.z - t.z; accb = fmaf(d, d, accb);                             \
        d = p.w - t.w; accb = fmaf(d, d, accb);                             \
        accr += (r.x >= 2.0f ? r.x : 0.0f) + (r.y >= 2.0f ? r.y : 0.0f)     \
              + (r.z >= 2.0f ? r.z : 0.0f) + (r.w >= 2.0f ? r.w : 0.0f);    \
        const int _b = (ii) * 4;                                            \
        UPD(p.x, _b);                                                       \
        UPD(p.y, _b + 1);                                                   \
        UPD(p.z, _b + 2);                                                   \
        UPD(p.w, _b + 3);                                                   \
    }

__global__ __launch_bounds__(TPB) void reward_pass1(
        const float* __restrict__ pred,
        const float* __restrict__ tru,
        const float* __restrict__ ret,
        double* __restrict__ blk_sum,
        u64* __restrict__ cand_k,
        int n) {
    const int tid = blockIdx.x * blockDim.x + threadIdx.x;
    const int nthreads = gridDim.x * blockDim.x;
    const int n4 = n >> 2;

    const float4* __restrict__ pred4 = (const float4*)pred;
    const float4* __restrict__ tru4  = (const float4*)tru;
    const float4* __restrict__ ret4  = (const float4*)ret;

    float accb = 0.0f;   // sum of (pred-true)^2
    float accr = 0.0f;   // sum of ret where ret >= 2 (rest_adj = 0.0015 * that)
    u64 k0 = 0, k1 = 0, k2 = 0, k3 = 0, k4 = 0;  // real keys are always > 0

    // Depth-4 batch: 12 x 16B loads in flight, single-BB body (branchless),
    // so the scheduler can pipeline loads across the whole unrolled body.
    int i = tid;
    for (; i + 3 * nthreads < n4; i += 4 * nthreads) {
        const int ia = i;
        const int ib = i + nthreads;
        const int ic = i + 2 * nthreads;
        const int id = i + 3 * nthreads;
        float4 pa = pred4[ia], pb = pred4[ib], pc = pred4[ic], pd = pred4[id];
        float4 ta = tru4[ia],  tb = tru4[ib],  tc = tru4[ic],  td = tru4[id];
        float4 ra = ret4[ia],  rb = ret4[ib],  rc = ret4[ic],  rd = ret4[id];
        PROC(pa, ta, ra, ia);
        PROC(pb, tb, rb, ib);
        PROC(pc, tc, rc, ic);
        PROC(pd, td, rd, id);
    }
    for (; i < n4; i += nthreads) {
        float4 p = pred4[i];
        float4 t = tru4[i];
        float4 r = ret4[i];
        PROC(p, t, r, i);
    }

    // Scalar tail (n not multiple of 4), handled by global thread 0.
    if (tid == 0) {
        for (int kk = n4 * 4; kk < n; ++kk) {
            float d = pred[kk] - tru[kk];
            accb = fmaf(d, d, accb);
            float rr = ret[kk];
            accr += (rr >= 2.0f ? rr : 0.0f);
            UPD(pred[kk], kk);
        }
    }

    const int lane = threadIdx.x & 63;
    const int wid  = threadIdx.x >> 6;

    // Block sum: wave shuffle reduce (double), then 4 wave partials via LDS.
    double acc = (double)accb + 0.0015 * (double)accr;
    for (int off = 32; off > 0; off >>= 1) acc += __shfl_down(acc, off);
    __shared__ double wsum[4];
    if (lane == 0) wsum[wid] = acc;
    __syncthreads();
    if (threadIdx.x == 0)
        blk_sum[blockIdx.x] = wsum[0] + wsum[1] + wsum[2] + wsum[3];

    // Block top-5: 5 rounds of (wave shfl argmax on keys -> cross-wave -> pop).
    __shared__ u64 bsk[4];
    for (int r = 0; r < 5; ++r) {
        const u64 ck = k0;
        u64 wk = ck;
        for (int off = 1; off < 64; off <<= 1) {
            u64 ok = __shfl_xor(wk, off);
            if (ok > wk) wk = ok;
        }
        if (lane == 0) bsk[wid] = wk;
        __syncthreads();
        u64 gk = bsk[0];
        if (bsk[1] > gk) gk = bsk[1];
        if (bsk[2] > gk) gk = bsk[2];
        if (bsk[3] > gk) gk = bsk[3];
        if (threadIdx.x == 0) cand_k[blockIdx.x * 5 + r] = gk;
        if (gk == ck) {  // keys unique -> exactly one owner pops
            k0 = k1; k1 = k2; k2 = k3; k3 = k4; k4 = 0;
        }
        __syncthreads();  // WAR: bsk reused next round
    }
}

__global__ __launch_bounds__(TPB) void reward_pass2(
        const double* __restrict__ blk_sum,
        const u64* __restrict__ cand_k,
        const float* __restrict__ ret,
        float* __restrict__ out,
        int nb, int n) {
    const int lane = threadIdx.x & 63;
    const int wid  = threadIdx.x >> 6;

    // Sum of partials.
    double acc = 0.0;
    for (int i = threadIdx.x; i < nb; i += TPB) acc += blk_sum[i];
    for (int off = 32; off > 0; off >>= 1) acc += __shfl_down(acc, off);
    __shared__ double wsum[4];
    if (lane == 0) wsum[wid] = acc;
    __syncthreads();

    // Per-thread top-5 over candidate keys (branchless ladder).
    u64 k0 = 0, k1 = 0, k2 = 0, k3 = 0, k4 = 0;
    const int nc = nb * 5;
    for (int i = threadIdx.x; i < nc; i += TPB) {
        const u64 _key = cand_k[i];
        const bool c0 = _key > k0;
        const bool c1 = _key > k1;
        const bool c2 = _key > k2;
        const bool c3 = _key > k3;
        const bool c4 = _key > k4;
        k4 = c3 ? k3 : (c4 ? _key : k4);
        k3 = c2 ? k2 : (c3 ? _key : k3);
        k2 = c1 ? k1 : (c2 ? _key : k2);
        k1 = c0 ? k0 : (c1 ? _key : k1);
        k0 = c0 ? _key : k0;
    }

    // 5 rounds block argmax + pop -> global top-5 indices.
    __shared__ u64 bsk[4];
    __shared__ int winner[5];
    for (int r = 0; r < 5; ++r) {
        const u64 ck = k0;
        u64 wk = ck;
        for (int off = 1; off < 64; off <<= 1) {
            u64 ok = __shfl_xor(wk, off);
            if (ok > wk) wk = ok;
        }
        if (lane == 0) bsk[wid] = wk;
        __syncthreads();
        u64 gk = bsk[0];
        if (bsk[1] > gk) gk = bsk[1];
        if (bsk[2] > gk) gk = bsk[2];
        if (bsk[3] > gk) gk = bsk[3];
        if (threadIdx.x == 0) winner[r] = (int)(~(u32)gk);
        if (gk == ck) {
            k0 = k1; k1 = k2; k2 = k3; k3 = k4; k4 = 0;
        }
        __syncthreads();
    }

    if (threadIdx.x == 0) {
        double corr = 0.0;
        for (int r = 0; r < 5; ++r) {
            int idx = winner[r];
            float rr = ret[idx];
            float a = fabsf(rr);
            float strict, mid;
            if (rr < 0.0f)       { strict = 0.005f * a;  mid = 0.0025f * a; }
            else if (rr >= 2.0f) { strict = -0.02f * rr; mid = -0.01f * rr; }
            else if (rr > 0.0f)  { strict = -0.01f * rr; mid = -0.005f * rr; }
            else                 { strict = 0.0f;        mid = 0.0f; }
            float rest = (rr >= 2.0f) ? 0.0015f * rr : 0.0f;
            float bucket = (r < 3) ? strict : mid;  // ranks 1..3 strict, 4..5 mid
            corr += (double)(bucket - rest);
        }
        out[0] = (float)((wsum[0] + wsum[1] + wsum[2] + wsum[3] + corr) / (double)n);
    }
}

extern "C" void kernel_launch(void* const* d_in, const int* in_sizes, int n_in,
                              void* d_out, int out_size, void* d_ws, size_t ws_size,
                              hipStream_t stream) {
    const float* pred = (const float*)d_in[0];
    const float* tru  = (const float*)d_in[1];
    const float* ret  = (const float*)d_in[2];
    float* out = (float*)d_out;
    const int n = in_sizes[0];

    int nb = 2048;
    // Per-block scratch: 8B sum + 5*8B candidate keys = 48B. Fit within ws_size.
    while (nb > 64 && (size_t)nb * 48 > ws_size) nb >>= 1;

    double* blk_sum = (double*)d_ws;
    u64*    cand_k  = (u64*)(blk_sum + nb);

    reward_pass1<<<nb, TPB, 0, stream>>>(pred, tru, ret, blk_sum, cand_k, n);
    reward_pass2<<<1, TPB, 0, stream>>>(blk_sum, cand_k, ret, out, nb, n);
}